// Round 8
// baseline (61.381 us; speedup 1.0000x reference)
//
#include <hip/hip_runtime.h>

// SphericalEmbedding round 8: store-duty-cycle attack.
//   k1: W [81,2048] f32 -> WT [2048][96] bf16 (d_ws+0)
//   k2: pos -> HG [32768][96] bf16 harmonics (d_ws+384KB)  [NEW]
//   k3: pure GEMM: A=WT rows, B=HG rows, both direct 16B global loads
//       (L2-resident), no harmonics phase, per-kk frag loads (low VGPR),
//       half-tile LDS C-staging (33.8KB) -> ~3 blocks/CU -> store pipe
//       stays busy across block boundaries.
// Fallback: R6 fused kernel if ws_size < 6.7MB.

typedef __attribute__((ext_vector_type(8))) short bf16x8;
typedef __attribute__((ext_vector_type(4))) float f32x4;

#define BM 128
#define BN 128
#define KPAD 96
#define LDCC 132         // C chunk row stride (dwords)
#define LDA 104          // fused-fallback H row stride (bf16)

// ---- compile-time normalization table ----------------------------------
constexpr double PI_D = 3.14159265358979323846;
constexpr double csqrt_c(double v) {
  if (v <= 0.0) return 0.0;
  double g = v < 1.0 ? 1.0 : v;
  for (int i = 0; i < 100; ++i) g = 0.5 * (g + v / g);
  return g;
}
struct Norms { float c[81]; };
constexpr Norms make_norms() {
  Norms n{};
  for (int l = 0; l <= 8; ++l)
    for (int m = -l; m <= l; ++m) {
      int am = m < 0 ? -m : m;
      double fr = 1.0;
      for (int i = l - am + 1; i <= l + am; ++i) fr *= (double)i;
      double v = csqrt_c((2.0 * l + 1.0) / (4.0 * PI_D) / fr);
      if (m < 0 && (am & 1)) v = -v;
      n.c[l * l + l + m] = (float)v;
    }
  return n;
}
constexpr Norms NORMS = make_norms();

__device__ __forceinline__ unsigned f2bf(float f) {   // RTN-even f32 -> bf16 bits
  unsigned u = __float_as_uint(f);
  return (u + 0x7fffu + ((u >> 16) & 1u)) >> 16;
}

// ---- shared harmonics math (per point) ---------------------------------
__device__ __forceinline__ void harmonics96(float px, float py, float pz,
                                            float* __restrict__ y) {
  const float r   = sqrtf(px * px + py * py + pz * pz);
  const float inv = 1.0f / (r + 1e-8f);
  const float xn = px * inv, yn = py * inv, zn = pz * inv;
  const float x = fminf(1.0f, fmaxf(-1.0f, zn));     // cos(theta)
  const float s = sqrtf(fmaxf(0.0f, 1.0f - x * x));  // sin(theta)
  const float rho = sqrtf(xn * xn + yn * yn);
  const float c1  = rho > 0.0f ? xn / rho : 1.0f;    // cos(phi)

  float cm[9];
  cm[0] = 1.0f; cm[1] = c1;
#pragma unroll
  for (int m = 2; m <= 8; ++m) cm[m] = 2.0f * c1 * cm[m - 1] - cm[m - 2];

  float P[9][9];
#pragma unroll
  for (int m = 0; m <= 8; ++m) {
    if (m == 0) P[0][0] = 1.0f;
    else        P[m][m] = -(float)(2 * m - 1) * s * P[m - 1][m - 1];
    if (m + 1 <= 8) P[m + 1][m] = (float)(2 * m + 1) * x * P[m][m];
#pragma unroll
    for (int l = m + 2; l <= 8; ++l)
      P[l][m] = ((float)(2 * l - 1) * x * P[l - 1][m]
                 - (float)(l + m - 1) * P[l - 2][m]) / (float)(l - m);
  }
#pragma unroll
  for (int l = 0; l <= 8; ++l)
#pragma unroll
    for (int m = -l; m <= l; ++m) {
      const int am  = m < 0 ? -m : m;
      const int idx = l * l + l + m;
      y[idx] = NORMS.c[idx] * P[l][am] * cm[am];
    }
#pragma unroll
  for (int i = 81; i < KPAD; ++i) y[i] = 0.0f;
}

// ---- k1: W f32 [81][nch] -> WT bf16 [nch][96] --------------------------
__global__ __launch_bounds__(256)
void wt_convert_kernel(const float* __restrict__ W, unsigned short* __restrict__ WT, int nch) {
  const int t = blockIdx.x * 256 + threadIdx.x;
  if (t >= nch * 12) return;
  const int kg = t / nch;
  const int c  = t - kg * nch;
  unsigned short v[8];
#pragma unroll
  for (int j = 0; j < 8; ++j) {
    const int k = kg * 8 + j;
    v[j] = (k < 81) ? (unsigned short)f2bf(W[(size_t)k * nch + c]) : (unsigned short)0;
  }
  unsigned* dst = reinterpret_cast<unsigned*>(WT + (size_t)c * KPAD + kg * 8);
#pragma unroll
  for (int j = 0; j < 4; ++j)
    dst[j] = (unsigned)v[2 * j] | ((unsigned)v[2 * j + 1] << 16);
}

// ---- k2: pos -> HG bf16 [npts][96] -------------------------------------
__global__ __launch_bounds__(256)
void harm_kernel(const float* __restrict__ pos, unsigned short* __restrict__ HG, int npts) {
  const int t = blockIdx.x * 256 + threadIdx.x;
  if (t >= npts) return;
  float y[KPAD];
  harmonics96(pos[t * 3 + 0], pos[t * 3 + 1], pos[t * 3 + 2], y);
  unsigned* dst = reinterpret_cast<unsigned*>(HG + (size_t)t * KPAD);
#pragma unroll
  for (int i = 0; i < KPAD / 2; ++i)
    dst[i] = f2bf(y[2 * i]) | (f2bf(y[2 * i + 1]) << 16);
}

// ---- k3: pure MFMA GEMM + half-tile staged epilogue --------------------
__global__ __launch_bounds__(256)
void gemm_kernel(const unsigned short* __restrict__ HG,
                 const unsigned short* __restrict__ WT,
                 float* __restrict__ out, int nch, int nmb)
{
  __shared__ __align__(16) float C[64 * LDCC];     // 33792 B half-tile
  const int orig = blockIdx.x;
  const int mblk = orig % nmb;                      // point-tile FASTEST
  const int nblk = orig / nmb;

  const int tid  = threadIdx.x;
  const int lane = tid & 63;
  const int wid  = tid >> 6;                        // 4 waves: 2(ch) x 2(pt)
  const int wc   = wid >> 1, wp = wid & 1;
  const int l15  = lane & 15, l4 = lane >> 4;

  const unsigned short* hg_base = HG + (size_t)(mblk * BM + wp * 64 + l15) * KPAD + l4 * 8;
  const unsigned short* wt_base = WT + (size_t)(nblk * BN + wc * 64 + l15) * KPAD + l4 * 8;

  f32x4 acc[4][4] = {};
#pragma unroll
  for (int kk = 0; kk < 3; ++kk) {
    bf16x8 wfrag[4], hfrag[4];
#pragma unroll
    for (int i = 0; i < 4; ++i)
      wfrag[i] = *reinterpret_cast<const bf16x8*>(wt_base + (size_t)i * 16 * KPAD + kk * 32);
#pragma unroll
    for (int i = 0; i < 4; ++i)
      hfrag[i] = *reinterpret_cast<const bf16x8*>(hg_base + (size_t)i * 16 * KPAD + kk * 32);
#pragma unroll
    for (int cmr = 0; cmr < 4; ++cmr)
#pragma unroll
      for (int pn = 0; pn < 4; ++pn)
        acc[cmr][pn] = __builtin_amdgcn_mfma_f32_16x16x32_bf16(
            wfrag[cmr], hfrag[pn], acc[cmr][pn], 0, 0, 0);
  }

  // epilogue: two half-tiles (pn = {0,1}, {2,3}) staged through LDS.
  // D row(ch) = wc*64 + cmr*16 + l4*4 + reg; D col(pt) = wp*64 + pn*16 + l15
  const size_t obase = (size_t)(mblk * BM) * nch + (size_t)nblk * BN;
#pragma unroll
  for (int h = 0; h < 2; ++h) {
#pragma unroll
    for (int q = 0; q < 2; ++q) {
      const int lr = wp * 32 + q * 16 + l15;        // local chunk row (point)
#pragma unroll
      for (int cmr = 0; cmr < 4; ++cmr)
        *reinterpret_cast<f32x4*>(&C[lr * LDCC + wc * 64 + cmr * 16 + l4 * 4]) =
            acc[cmr][2 * h + q];
    }
    __syncthreads();
#pragma unroll
    for (int it = 0; it < 8; ++it) {
      const int f  = it * 1024 + tid * 4;           // flat float idx in chunk
      const int lr = f >> 7;                        // chunk row 0..63
      const int cc = f & 127;                       // channel col
      const int gr = (lr >> 5) * 64 + h * 32 + (lr & 31);   // global point row
      const f32x4 v = *reinterpret_cast<const f32x4*>(&C[lr * LDCC + cc]);
      *reinterpret_cast<f32x4*>(out + obase + (size_t)gr * nch + cc) = v;
    }
    if (h == 0) __syncthreads();
  }
}

// ---- fallback: R6 fused kernel (proven 55.4us) -------------------------
__global__ __launch_bounds__(256)
void sph_mfma_fused(const float* __restrict__ pos,
                    const unsigned short* __restrict__ WT,
                    float* __restrict__ out, int nch)
{
  __shared__ __align__(16) char smem[BM * LDCC * 4];
  unsigned short* H = reinterpret_cast<unsigned short*>(smem);
  float*          C = reinterpret_cast<float*>(smem);

  const int tid  = threadIdx.x;
  const int lane = tid & 63;
  const int wid  = tid >> 6;
  const int wc   = wid >> 1, wp = wid & 1;
  const int l15  = lane & 15, l4 = lane >> 4;
  const int mblk = blockIdx.y, nblk = blockIdx.x;

  if (tid < BM) {
    const int gp = mblk * BM + tid;
    float y[KPAD];
    harmonics96(pos[gp * 3 + 0], pos[gp * 3 + 1], pos[gp * 3 + 2], y);
    unsigned* hrow = reinterpret_cast<unsigned*>(&H[tid * LDA]);
#pragma unroll
    for (int i = 0; i < KPAD / 2; ++i)
      hrow[i] = f2bf(y[2 * i]) | (f2bf(y[2 * i + 1]) << 16);
  }

  bf16x8 wfrag[3][4];
  const unsigned short* wt_base =
      WT + (size_t)(nblk * BN + wc * 64 + l15) * KPAD + l4 * 8;
#pragma unroll
  for (int kk = 0; kk < 3; ++kk)
#pragma unroll
    for (int cmr = 0; cmr < 4; ++cmr)
      wfrag[kk][cmr] = *reinterpret_cast<const bf16x8*>(
          wt_base + (size_t)cmr * 16 * KPAD + kk * 32);

  __syncthreads();

  f32x4 acc[4][4] = {};
#pragma unroll
  for (int kk = 0; kk < 3; ++kk) {
    bf16x8 hfrag[4];
#pragma unroll
    for (int pn = 0; pn < 4; ++pn)
      hfrag[pn] = *reinterpret_cast<const bf16x8*>(
          &H[(wp * 64 + pn * 16 + l15) * LDA + kk * 32 + l4 * 8]);
#pragma unroll
    for (int cmr = 0; cmr < 4; ++cmr)
#pragma unroll
      for (int pn = 0; pn < 4; ++pn)
        acc[cmr][pn] = __builtin_amdgcn_mfma_f32_16x16x32_bf16(
            wfrag[kk][cmr], hfrag[pn], acc[cmr][pn], 0, 0, 0);
  }

  __syncthreads();
#pragma unroll
  for (int pn = 0; pn < 4; ++pn) {
    const int crow = wp * 64 + pn * 16 + l15;
#pragma unroll
    for (int cmr = 0; cmr < 4; ++cmr)
      *reinterpret_cast<f32x4*>(&C[crow * LDCC + wc * 64 + cmr * 16 + l4 * 4]) =
          acc[cmr][pn];
  }
  __syncthreads();

  const size_t obase = (size_t)(mblk * BM) * nch + (size_t)nblk * BN;
#pragma unroll
  for (int i = 0; i < 16; ++i) {
    const int f = i * 1024 + tid * 4;
    const int r = f >> 7;
    const int c = f & 127;
    const f32x4 v = *reinterpret_cast<const f32x4*>(&C[r * LDCC + c]);
    *reinterpret_cast<f32x4*>(out + obase + (size_t)r * nch + c) = v;
  }
}

extern "C" void kernel_launch(void* const* d_in, const int* in_sizes, int n_in,
                              void* d_out, int out_size, void* d_ws, size_t ws_size,
                              hipStream_t stream) {
  const float* pos = (const float*)d_in[0];   // [npts, 3]
  const float* W   = (const float*)d_in[1];   // [81, nch]
  float*       out = (float*)d_out;           // [npts, nch]
  const int npts = in_sizes[0] / 3;           // 32768
  const int nch  = in_sizes[1] / 81;          // 2048

  const size_t wt_bytes = (size_t)nch * KPAD * sizeof(unsigned short);   // 384 KB
  const size_t hg_bytes = (size_t)npts * KPAD * sizeof(unsigned short);  // 6.3 MB

  unsigned short* WT = (unsigned short*)d_ws;
  wt_convert_kernel<<<(nch * 12 + 255) / 256, 256, 0, stream>>>(W, WT, nch);

  if (ws_size >= wt_bytes + hg_bytes) {
    unsigned short* HG = (unsigned short*)((char*)d_ws + wt_bytes);
    harm_kernel<<<(npts + 255) / 256, 256, 0, stream>>>(pos, HG, npts);
    const int nmb = npts / BM;                 // 256 (fastest)
    const int nwg = nmb * (nch / BN);          // 4096
    gemm_kernel<<<nwg, 256, 0, stream>>>(HG, WT, out, nch, nmb);
  } else {
    dim3 grid(nch / BN, npts / BM);
    sph_mfma_fused<<<grid, 256, 0, stream>>>(pos, WT, out, nch);
  }
}

// Round 10
// 56.732 us; speedup vs baseline: 1.0820x; 1.0820x over previous
//
#include <hip/hip_runtime.h>

// SphericalEmbedding round 10: occupancy attack, no allocator cap (R9's
// launch_bounds(256,4) is the prime suspect for its corruption).
//   - Phase 1 streams harmonics per-m directly into LDS via b16 stores:
//     no P[9][9], no y[96] -> ~25 live regs in phase 1.
//   - Per-kk fragment loads -> steady state ~115 VGPR (under the 128 cliff).
//   - Half-tile x2 LDS C-staging (33.8 KB, proven in R8) -> 4 blocks/CU.

typedef __attribute__((ext_vector_type(8))) short bf16x8;
typedef __attribute__((ext_vector_type(4))) float f32x4;

#define BM 128
#define BN 128
#define LDA 104          // H row stride (bf16): 208 B -> 2-way aliasing (free)
#define KPAD 96
#define LDCC 132         // C chunk row stride (dwords)

// ---- compile-time normalization table ----------------------------------
constexpr double PI_D = 3.14159265358979323846;
constexpr double csqrt_c(double v) {
  if (v <= 0.0) return 0.0;
  double g = v < 1.0 ? 1.0 : v;
  for (int i = 0; i < 100; ++i) g = 0.5 * (g + v / g);
  return g;
}
struct Norms { float c[81]; };
constexpr Norms make_norms() {
  Norms n{};
  for (int l = 0; l <= 8; ++l)
    for (int m = -l; m <= l; ++m) {
      int am = m < 0 ? -m : m;
      double fr = 1.0;
      for (int i = l - am + 1; i <= l + am; ++i) fr *= (double)i;
      double v = csqrt_c((2.0 * l + 1.0) / (4.0 * PI_D) / fr);
      if (m < 0 && (am & 1)) v = -v;
      n.c[l * l + l + m] = (float)v;
    }
  return n;
}
constexpr Norms NORMS = make_norms();

__device__ __forceinline__ unsigned f2bf(float f) {   // RTN-even f32 -> bf16 bits
  unsigned u = __float_as_uint(f);
  return (u + 0x7fffu + ((u >> 16) & 1u)) >> 16;
}

// ---- pre-kernel: W f32 [81][nch] -> WT bf16 [nch][96] (padded) ---------
__global__ __launch_bounds__(256)
void wt_convert_kernel(const float* __restrict__ W, unsigned short* __restrict__ WT, int nch) {
  const int t = blockIdx.x * 256 + threadIdx.x;
  if (t >= nch * 12) return;
  const int kg = t / nch;
  const int c  = t - kg * nch;
  unsigned short v[8];
#pragma unroll
  for (int j = 0; j < 8; ++j) {
    const int k = kg * 8 + j;
    v[j] = (k < 81) ? (unsigned short)f2bf(W[(size_t)k * nch + c]) : (unsigned short)0;
  }
  unsigned* dst = reinterpret_cast<unsigned*>(WT + (size_t)c * KPAD + kg * 8);
#pragma unroll
  for (int j = 0; j < 4; ++j)
    dst[j] = (unsigned)v[2 * j] | ((unsigned)v[2 * j + 1] << 16);
}

// ---- main MFMA kernel ---------------------------------------------------
__global__ __launch_bounds__(256)
void sph_mfma_kernel(const float* __restrict__ pos,
                     const unsigned short* __restrict__ WT,
                     float* __restrict__ out, int nch)
{
  // H (bf16, 26.6 KB) and C half-tile (64x132 f32 = 33.8 KB) time-share.
  __shared__ __align__(16) char smem[64 * LDCC * 4];       // 33792 B
  unsigned short* H = reinterpret_cast<unsigned short*>(smem);
  float*          C = reinterpret_cast<float*>(smem);

  const int tid  = threadIdx.x;
  const int lane = tid & 63;
  const int wid  = tid >> 6;                       // 4 waves: 2(ch) x 2(pt)
  const int wc   = wid >> 1, wp = wid & 1;
  const int l15  = lane & 15, l4 = lane >> 4;
  const int mblk = blockIdx.y, nblk = blockIdx.x;

  // ---- phase 1: streaming harmonics -> direct b16 LDS writes ------------
  if (tid < BM) {
    const int gp = mblk * BM + tid;
    const float px = pos[gp * 3 + 0];
    const float py = pos[gp * 3 + 1];
    const float pz = pos[gp * 3 + 2];
    const float r   = sqrtf(px * px + py * py + pz * pz);
    const float inv = 1.0f / (r + 1e-8f);
    const float xn = px * inv, yn = py * inv, zn = pz * inv;
    const float x = fminf(1.0f, fmaxf(-1.0f, zn));     // cos(theta)
    const float s = sqrtf(fmaxf(0.0f, 1.0f - x * x));  // sin(theta)
    const float rho = sqrtf(xn * xn + yn * yn);
    const float c1  = rho > 0.0f ? xn / rho : 1.0f;    // cos(phi)

    float cm[9];
    cm[0] = 1.0f; cm[1] = c1;
#pragma unroll
    for (int m = 2; m <= 8; ++m) cm[m] = 2.0f * c1 * cm[m - 1] - cm[m - 2];

    unsigned short* hrow = &H[tid * LDA];
    float Pmm_prev = 1.0f;                 // P_{m-1}^{m-1} carry
#pragma unroll
    for (int m = 0; m <= 8; ++m) {
      const float Pmm = (m == 0) ? 1.0f : -(float)(2 * m - 1) * s * Pmm_prev;
      Pmm_prev = Pmm;
      {
        const float base = Pmm * cm[m];                    // l = m
        hrow[m * m + 2 * m] = (unsigned short)f2bf(NORMS.c[m * m + 2 * m] * base);
        if (m > 0)
          hrow[m * m] = (unsigned short)f2bf(NORMS.c[m * m] * base);
      }
      float Pl2 = Pmm, Pl1 = 0.0f;
      if (m + 1 <= 8) {
        Pl1 = (float)(2 * m + 1) * x * Pmm;                // l = m+1
        const int l = m + 1;
        const float base = Pl1 * cm[m];
        hrow[l * l + l + m] = (unsigned short)f2bf(NORMS.c[l * l + l + m] * base);
        if (m > 0)
          hrow[l * l + l - m] = (unsigned short)f2bf(NORMS.c[l * l + l - m] * base);
      }
#pragma unroll
      for (int l = m + 2; l <= 8; ++l) {
        const float Pl = ((float)(2 * l - 1) * x * Pl1
                          - (float)(l + m - 1) * Pl2) * (1.0f / (float)(l - m));
        Pl2 = Pl1; Pl1 = Pl;
        const float base = Pl * cm[m];
        hrow[l * l + l + m] = (unsigned short)f2bf(NORMS.c[l * l + l + m] * base);
        if (m > 0)
          hrow[l * l + l - m] = (unsigned short)f2bf(NORMS.c[l * l + l - m] * base);
      }
    }
#pragma unroll
    for (int i = 81; i < KPAD; ++i) hrow[i] = 0;           // K padding
  }

  __syncthreads();

  // ---- MFMA: D[ch, pt], per-kk fragment loads ---------------------------
  const unsigned short* wt_base =
      WT + (size_t)(nblk * BN + wc * 64 + l15) * KPAD + l4 * 8;
  f32x4 acc[4][4] = {};
#pragma unroll
  for (int kk = 0; kk < 3; ++kk) {
    bf16x8 wfrag[4], hfrag[4];
#pragma unroll
    for (int i = 0; i < 4; ++i)
      wfrag[i] = *reinterpret_cast<const bf16x8*>(
          wt_base + (size_t)i * 16 * KPAD + kk * 32);
#pragma unroll
    for (int i = 0; i < 4; ++i)
      hfrag[i] = *reinterpret_cast<const bf16x8*>(
          &H[(wp * 64 + i * 16 + l15) * LDA + kk * 32 + l4 * 8]);
#pragma unroll
    for (int cmr = 0; cmr < 4; ++cmr)
#pragma unroll
      for (int pn = 0; pn < 4; ++pn)
        acc[cmr][pn] = __builtin_amdgcn_mfma_f32_16x16x32_bf16(
            wfrag[cmr], hfrag[pn], acc[cmr][pn], 0, 0, 0);
  }

  __syncthreads();   // H dead; smem becomes the C half-tile

  // ---- epilogue: two half-tile passes through LDS (R8-proven) ------------
  // D row(ch) = wc*64 + cmr*16 + l4*4 + reg; D col(pt) = wp*64 + pn*16 + l15
  const size_t obase = (size_t)(mblk * BM) * nch + (size_t)nblk * BN;
#pragma unroll
  for (int h = 0; h < 2; ++h) {
#pragma unroll
    for (int q = 0; q < 2; ++q) {
      const int lr = wp * 32 + q * 16 + l15;        // local chunk row (point)
#pragma unroll
      for (int cmr = 0; cmr < 4; ++cmr)
        *reinterpret_cast<f32x4*>(&C[lr * LDCC + wc * 64 + cmr * 16 + l4 * 4]) =
            acc[cmr][2 * h + q];
    }
    __syncthreads();
#pragma unroll
    for (int it = 0; it < 8; ++it) {
      const int f  = it * 1024 + tid * 4;           // flat float idx in chunk
      const int lr = f >> 7;                        // chunk row 0..63
      const int cc = f & 127;                       // channel col
      const int gr = (lr >> 5) * 64 + h * 32 + (lr & 31);   // block point row
      const f32x4 v = *reinterpret_cast<const f32x4*>(&C[lr * LDCC + cc]);
      *reinterpret_cast<f32x4*>(out + obase + (size_t)gr * nch + cc) = v;
    }
    if (h == 0) __syncthreads();
  }
}

extern "C" void kernel_launch(void* const* d_in, const int* in_sizes, int n_in,
                              void* d_out, int out_size, void* d_ws, size_t ws_size,
                              hipStream_t stream) {
  const float* pos = (const float*)d_in[0];   // [npts, 3]
  const float* W   = (const float*)d_in[1];   // [81, nch]
  float*       out = (float*)d_out;           // [npts, nch]
  const int npts = in_sizes[0] / 3;           // 32768
  const int nch  = in_sizes[1] / 81;          // 2048

  unsigned short* WT = (unsigned short*)d_ws;  // 384 KB
  wt_convert_kernel<<<(nch * 12 + 255) / 256, 256, 0, stream>>>(W, WT, nch);
  dim3 grid(nch / BN, npts / BM);              // (16, 256)
  sph_mfma_kernel<<<grid, 256, 0, stream>>>(pos, WT, out, nch);
}